// Round 3
// baseline (505.363 us; speedup 1.0000x reference)
//
#include <hip/hip_runtime.h>

#define B_ 4
#define C_ 4
#define V_ 262144
#define F_ 64
#define K_ 100
#define THETA 0.9f
#define TAU_ 0.1f
#define CAP2 4096

typedef unsigned long long ull;

// ---------------- workspace layout (bytes) ----------------
// cs     : 0       .. 1024     (C*F floats, [c][f])
// cnt    : 1024    .. 1040     (C floats)
// hist1  : 2048    .. 6144     (B*256 u32)
// hist2  : 6144    .. 10240    (B*256 u32)
// ctrl1  : 10240   .. 10272    (B*2 u32: T1, n_above)
// ctrl2  : 10272   .. 10304    (B*2 u32: P16, n_above2)
// ccount : 10304   .. 10320    (B u32)
// idxout : 10368   .. 11968    (B*K u32)
// cbits  : 16384   .. 81920    (B*CAP2 u32)
// cidx   : 81920   .. 147456   (B*CAP2 u32)
// wbits  : 1048576 .. 5242880  (B*V u32 — product weights' float bits)

__global__ void k_init(float* cs, float* cnt, unsigned* hist1, unsigned* hist2, unsigned* ccount) {
    int t = blockIdx.x * blockDim.x + threadIdx.x;
    if (t < C_ * F_) cs[t] = 0.f;
    if (t < C_) cnt[t] = 0.f;
    if (t < B_ * 256) { hist1[t] = 0u; hist2[t] = 0u; }
    if (t < B_) ccount[t] = 0u;
}

// class_sum[c][f] += emb[b,f,v] * (y[b,c,v]>0); count[c] += mask
// grid: B*256 blocks, each owns (b, 1024-v chunk).
// Phase A: stage 4-bit/v class mask in LDS from coalesced y reads (y read once).
// Phase B: wave w handles 16 f-rows; fully-coalesced float4 emb stream.
__global__ __launch_bounds__(256) void k_class_sum(const float* __restrict__ emb,
                                                   const int* __restrict__ y,
                                                   float* __restrict__ cs,
                                                   float* __restrict__ cnt) {
    __shared__ unsigned msk[256];   // u32: byte j = class-bit mask of v=4*slot+j
    __shared__ unsigned wcnt[4][2];
    int b = blockIdx.x >> 8;
    int base = (blockIdx.x & 255) << 10;
    int tid = threadIdx.x;
    int wave = tid >> 6, lane = tid & 63;

    // ---- phase A: masks + counts ----
    const int4* y0 = (const int4*)(y + ((size_t)(b * C_ + 0)) * V_ + base);
    const int4* y1 = (const int4*)(y + ((size_t)(b * C_ + 1)) * V_ + base);
    const int4* y2 = (const int4*)(y + ((size_t)(b * C_ + 2)) * V_ + base);
    const int4* y3 = (const int4*)(y + ((size_t)(b * C_ + 3)) * V_ + base);
    int4 ya = y0[tid], yb = y1[tid], yc = y2[tid], yd = y3[tid];

    unsigned b0 = (unsigned)(ya.x > 0) | ((unsigned)(yb.x > 0) << 1) | ((unsigned)(yc.x > 0) << 2) | ((unsigned)(yd.x > 0) << 3);
    unsigned b1 = (unsigned)(ya.y > 0) | ((unsigned)(yb.y > 0) << 1) | ((unsigned)(yc.y > 0) << 2) | ((unsigned)(yd.y > 0) << 3);
    unsigned b2 = (unsigned)(ya.z > 0) | ((unsigned)(yb.z > 0) << 1) | ((unsigned)(yc.z > 0) << 2) | ((unsigned)(yd.z > 0) << 3);
    unsigned b3 = (unsigned)(ya.w > 0) | ((unsigned)(yb.w > 0) << 1) | ((unsigned)(yc.w > 0) << 2) | ((unsigned)(yd.w > 0) << 3);
    msk[tid] = b0 | (b1 << 8) | (b2 << 16) | (b3 << 24);

    unsigned p01 = ((unsigned)(ya.x > 0) + (ya.y > 0) + (ya.z > 0) + (ya.w > 0))
                 | (((unsigned)(yb.x > 0) + (yb.y > 0) + (yb.z > 0) + (yb.w > 0)) << 16);
    unsigned p23 = ((unsigned)(yc.x > 0) + (yc.y > 0) + (yc.z > 0) + (yc.w > 0))
                 | (((unsigned)(yd.x > 0) + (yd.y > 0) + (yd.z > 0) + (yd.w > 0)) << 16);
    #pragma unroll
    for (int o = 1; o < 64; o <<= 1) {
        p01 += __shfl_xor(p01, o, 64);
        p23 += __shfl_xor(p23, o, 64);
    }
    if (lane == 0) { wcnt[wave][0] = p01; wcnt[wave][1] = p23; }
    __syncthreads();
    if (tid == 0) {
        unsigned q01 = wcnt[0][0] + wcnt[1][0] + wcnt[2][0] + wcnt[3][0];
        unsigned q23 = wcnt[0][1] + wcnt[1][1] + wcnt[2][1] + wcnt[3][1];
        atomicAdd(&cnt[0], (float)(q01 & 0xFFFFu));
        atomicAdd(&cnt[1], (float)(q01 >> 16));
        atomicAdd(&cnt[2], (float)(q23 & 0xFFFFu));
        atomicAdd(&cnt[3], (float)(q23 >> 16));
    }

    // ---- phase B: streamed emb, 16 rows per wave ----
    for (int r = 0; r < 16; ++r) {
        int f = (wave << 4) | r;
        const float4* ep = (const float4*)(emb + ((size_t)(b * F_ + f)) * V_ + base);
        float a0 = 0.f, a1 = 0.f, a2 = 0.f, a3 = 0.f;
        #pragma unroll
        for (int it = 0; it < 4; ++it) {
            int s = (it << 6) | lane;
            float4 e = ep[s];
            unsigned m = msk[s];
            a0 += e.x * (float)( m        & 1u) + e.y * (float)((m >>  8) & 1u)
                + e.z * (float)((m >> 16) & 1u) + e.w * (float)((m >> 24) & 1u);
            a1 += e.x * (float)((m >>  1) & 1u) + e.y * (float)((m >>  9) & 1u)
                + e.z * (float)((m >> 17) & 1u) + e.w * (float)((m >> 25) & 1u);
            a2 += e.x * (float)((m >>  2) & 1u) + e.y * (float)((m >> 10) & 1u)
                + e.z * (float)((m >> 18) & 1u) + e.w * (float)((m >> 26) & 1u);
            a3 += e.x * (float)((m >>  3) & 1u) + e.y * (float)((m >> 11) & 1u)
                + e.z * (float)((m >> 19) & 1u) + e.w * (float)((m >> 27) & 1u);
        }
        #pragma unroll
        for (int o = 1; o < 64; o <<= 1) {
            a0 += __shfl_xor(a0, o, 64);
            a1 += __shfl_xor(a1, o, 64);
            a2 += __shfl_xor(a2, o, 64);
            a3 += __shfl_xor(a3, o, 64);
        }
        if (lane == 0) {
            atomicAdd(&cs[0 * F_ + f], a0);
            atomicAdd(&cs[1 * F_ + f], a1);
            atomicAdd(&cs[2 * F_ + f], a2);
            atomicAdd(&cs[3 * F_ + f], a3);
        }
    }
}

__device__ __forceinline__ float weight_of(const float* __restrict__ p0, int v) {
    return ((p0[v] * p0[v + V_]) * p0[v + 2 * V_]) * p0[v + 3 * V_];
}

// level-1 histogram: top-8 bits of w; also materialize w bits for later passes
__global__ __launch_bounds__(256) void k_hist1(const float* __restrict__ proba,
                                               unsigned* __restrict__ hist1,
                                               unsigned* __restrict__ wbits) {
    __shared__ unsigned lh[256];
    int tid = threadIdx.x;
    lh[tid] = 0u;
    __syncthreads();
    int b = blockIdx.x >> 8;
    int base = (blockIdx.x & 255) << 10;
    const float* p0 = proba + (size_t)(b * C_) * V_;
    for (int it = 0; it < 4; ++it) {
        int v = base + tid + (it << 8);
        unsigned bits = __float_as_uint(weight_of(p0, v));
        wbits[(size_t)b * V_ + v] = bits;
        atomicAdd(&lh[bits >> 24], 1u);
    }
    __syncthreads();
    if (lh[tid]) atomicAdd(&hist1[b * 256 + tid], lh[tid]);
}

// level-2 histogram: next 8 bits, only for elements in bin T1 (reads wbits, 4 MB)
__global__ __launch_bounds__(256) void k_hist2(const unsigned* __restrict__ wbits,
                                               const unsigned* __restrict__ ctrl1,
                                               unsigned* __restrict__ hist2) {
    __shared__ unsigned lh[256];
    int tid = threadIdx.x;
    lh[tid] = 0u;
    __syncthreads();
    int b = blockIdx.x >> 8;
    int base = (blockIdx.x & 255) << 10;
    unsigned T1 = ctrl1[b * 2];
    for (int it = 0; it < 4; ++it) {
        int v = base + tid + (it << 8);
        unsigned bits = wbits[(size_t)b * V_ + v];
        if ((bits >> 24) == T1) atomicAdd(&lh[(bits >> 16) & 0xFF], 1u);
    }
    __syncthreads();
    if (lh[tid]) atomicAdd(&hist2[b * 256 + tid], lh[tid]);
}

// wave-parallel threshold finder over a 256-bin histogram (descending).
__global__ __launch_bounds__(256) void k_thresh(const unsigned* __restrict__ hist,
                                                const unsigned* __restrict__ ctrl_in,
                                                unsigned* __restrict__ ctrl_out,
                                                int lvl) {
    int b = threadIdx.x >> 6;
    int lane = threadIdx.x & 63;
    const unsigned* h = hist + b * 256;
    unsigned base = lvl ? ctrl_in[b * 2 + 1] : 0u;
    int binbase = 255 - 4 * lane;
    unsigned c0 = h[binbase], c1 = h[binbase - 1], c2 = h[binbase - 2], c3 = h[binbase - 3];
    unsigned cnt4 = c0 + c1 + c2 + c3;
    unsigned pref = cnt4;
    #pragma unroll
    for (int o = 1; o < 64; o <<= 1) {
        unsigned u = __shfl_up(pref, o, 64);
        if (lane >= o) pref += u;
    }
    unsigned above = base + pref - cnt4;
    unsigned t = above;
    int found = -1; unsigned nab = 0;
    if (t + c0 >= K_)                { found = binbase;     nab = t; }
    else if (t + c0 + c1 >= K_)      { found = binbase - 1; nab = t + c0; }
    else if (t + c0 + c1 + c2 >= K_) { found = binbase - 2; nab = t + c0 + c1; }
    else if (t + cnt4 >= K_)         { found = binbase - 3; nab = t + c0 + c1 + c2; }
    if (found >= 0 && above < K_) {
        ctrl_out[b * 2] = lvl ? ((ctrl_in[b * 2] << 8) | (unsigned)found) : (unsigned)found;
        ctrl_out[b * 2 + 1] = nab;
    }
}

// collect all candidates with (bits>>16) >= P16  (~K + one 16-bit bin)
__global__ __launch_bounds__(256) void k_collect(const unsigned* __restrict__ wbits,
                                                 const unsigned* __restrict__ ctrl2,
                                                 unsigned* __restrict__ ccount,
                                                 unsigned* __restrict__ cbits,
                                                 unsigned* __restrict__ cidx) {
    int b = blockIdx.x >> 8;
    int base = (blockIdx.x & 255) << 10;
    int tid = threadIdx.x;
    unsigned P16 = ctrl2[b * 2];
    for (int it = 0; it < 4; ++it) {
        int v = base + tid + (it << 8);
        unsigned bits = wbits[(size_t)b * V_ + v];
        if ((bits >> 16) >= P16) {
            unsigned pos = atomicAdd(&ccount[b], 1u);
            if (pos < CAP2) { cbits[b * CAP2 + pos] = bits; cidx[b * CAP2 + pos] = (unsigned)v; }
        }
    }
}

// exact top-K: one wave per b, lane-private LDS regions, zero barriers.
__global__ __launch_bounds__(64) void k_select(const unsigned* __restrict__ ccount,
                                               const unsigned* __restrict__ cbits,
                                               const unsigned* __restrict__ cidx,
                                               unsigned* __restrict__ idxout) {
    __shared__ ull keys[CAP2];
    int b = blockIdx.x;
    int lane = threadIdx.x;
    unsigned nc = ccount[b];
    int n = (int)(nc < CAP2 ? nc : CAP2);
    for (int i = lane; i < n; i += 64)
        keys[i] = ((ull)cbits[b * CAP2 + i] << 32) | (unsigned)(~cidx[b * CAP2 + i]);
    for (int k = 0; k < K_; ++k) {
        ull m = 0ull; int mslot = -1;
        for (int i = lane; i < n; i += 64) {
            ull key = keys[i];
            if (key > m) { m = key; mslot = i; }
        }
        ull lm = m;
        #pragma unroll
        for (int o = 1; o < 64; o <<= 1) {
            ull other = __shfl_xor(m, o, 64);
            if (other > m) m = other;
        }
        if (mslot >= 0 && lm == m) keys[mslot] = 0ull;
        if (lane == 0) idxout[b * K_ + k] = ~(unsigned)(m & 0xFFFFFFFFull);
    }
}

// final: one wave (64 lanes = F) per (b,k)
__global__ __launch_bounds__(64) void k_final(const float* __restrict__ emb,
                                              const int* __restrict__ y,
                                              const float* __restrict__ avg,
                                              const float* __restrict__ cs,
                                              const float* __restrict__ cnt,
                                              const unsigned* __restrict__ idxout,
                                              float* __restrict__ out) {
    int blk = blockIdx.x;
    int b = blk / K_;
    int k = blk % K_;
    int lane = threadIdx.x;
    unsigned v = idxout[b * K_ + k];

    float e = emb[((size_t)(b * F_ + lane)) * V_ + v];

    int y0v = y[((size_t)(b * C_ + 0)) * V_ + v];
    int y1v = y[((size_t)(b * C_ + 1)) * V_ + v];
    int y2v = y[((size_t)(b * C_ + 2)) * V_ + v];
    int y3v = y[((size_t)(b * C_ + 3)) * V_ + v];
    int cm = (y0v > 0) ? 0 : ((y1v > 0) ? 1 : ((y2v > 0) ? 2 : ((y3v > 0) ? 3 : 0)));
    float sel = (cm == 0) ? 1.f : 0.f;

    float t = e / TAU_;
    float ssum = 0.f;
    #pragma unroll
    for (int c = 1; c < 4; ++c) {
        float cc = cnt[c];
        float mean = cs[c * F_ + lane] / fmaxf(cc, 1.f);
        float av = avg[c * F_ + lane];
        float nar = (cc > 0.f) ? (av * (1.f - THETA) + mean * THETA) : av;
        ssum += expf(t * nar);
    }
    float term = -logf(ssum);
    #pragma unroll
    for (int o = 32; o > 0; o >>= 1) term += __shfl_down(term, o, 64);
    if (lane == 0) out[b * K_ + k] = term * sel;
}

extern "C" void kernel_launch(void* const* d_in, const int* in_sizes, int n_in,
                              void* d_out, int out_size, void* d_ws, size_t ws_size,
                              hipStream_t stream) {
    const float* proba = (const float*)d_in[0];
    const int* y = (const int*)d_in[1];
    const float* emb = (const float*)d_in[2];
    const float* avg = (const float*)d_in[3];
    float* out = (float*)d_out;

    char* ws = (char*)d_ws;
    float* cs = (float*)(ws + 0);
    float* cnt = (float*)(ws + 1024);
    unsigned* hist1 = (unsigned*)(ws + 2048);
    unsigned* hist2 = (unsigned*)(ws + 6144);
    unsigned* ctrl1 = (unsigned*)(ws + 10240);
    unsigned* ctrl2 = (unsigned*)(ws + 10272);
    unsigned* ccount = (unsigned*)(ws + 10304);
    unsigned* idxout = (unsigned*)(ws + 10368);
    unsigned* cbits = (unsigned*)(ws + 16384);
    unsigned* cidx = (unsigned*)(ws + 81920);
    unsigned* wbits = (unsigned*)(ws + 1048576);

    k_init<<<4, 256, 0, stream>>>(cs, cnt, hist1, hist2, ccount);
    k_class_sum<<<B_ * 256, 256, 0, stream>>>(emb, y, cs, cnt);
    k_hist1<<<B_ * 256, 256, 0, stream>>>(proba, hist1, wbits);
    k_thresh<<<1, 256, 0, stream>>>(hist1, nullptr, ctrl1, 0);
    k_hist2<<<B_ * 256, 256, 0, stream>>>(wbits, ctrl1, hist2);
    k_thresh<<<1, 256, 0, stream>>>(hist2, ctrl1, ctrl2, 1);
    k_collect<<<B_ * 256, 256, 0, stream>>>(wbits, ctrl2, ccount, cbits, cidx);
    k_select<<<B_, 64, 0, stream>>>(ccount, cbits, cidx, idxout);
    k_final<<<B_ * K_, 64, 0, stream>>>(emb, y, avg, cs, cnt, idxout, out);
}

// Round 4
// 212.201 us; speedup vs baseline: 2.3815x; 2.3815x over previous
//
#include <hip/hip_runtime.h>

#define B_ 4
#define C_ 4
#define V_ 262144
#define F_ 64
#define K_ 100
#define THETA 0.9f
#define TAU_ 0.1f
#define CAP2 4096

typedef unsigned long long ull;

// ---------------- workspace layout (bytes) ----------------
// cs     : 0       .. 1024     (C*F floats, [c][f])
// cnt    : 1024    .. 1040     (C floats)
// hist1  : 2048    .. 6144     (B*256 u32)
// hist2  : 6144    .. 10240    (B*256 u32)
// ctrl1  : 10240   .. 10272    (B*2 u32: T1, n_above)
// ctrl2  : 10272   .. 10304    (B*2 u32: P16, n_above2)
// ccount : 10304   .. 10320    (B u32)
// idxout : 10368   .. 11968    (B*K u32)
// cbits  : 16384   .. 81920    (B*CAP2 u32)
// cidx   : 81920   .. 147456   (B*CAP2 u32)
// wbits  : 1048576 .. 5242880  (B*V u32 — product weights' float bits)

__global__ void k_init(float* cs, float* cnt, unsigned* hist1, unsigned* hist2, unsigned* ccount) {
    int t = blockIdx.x * blockDim.x + threadIdx.x;
    if (t < C_ * F_) cs[t] = 0.f;
    if (t < C_) cnt[t] = 0.f;
    if (t < B_ * 256) { hist1[t] = 0u; hist2[t] = 0u; }
    if (t < B_) ccount[t] = 0u;
}

// class_sum[c][f] += emb[b,f,v] * (y[b,c,v]>0); count[c] += mask
// grid: B*256 blocks, each owns (b, 1024-v chunk), 256 threads.
// Phase A: 4-bit/v class masks into LDS (y read once, coalesced int4).
// Phase B: per wave, 4 passes; per pass 4 rows (r=lane>>4), q=lane&15 walks
//          16 contiguous float4 -> 16 loads in flight, per-thread accumulators,
//          one 4-step 16-lane reduce per pass.
__global__ __launch_bounds__(256) void k_class_sum(const float* __restrict__ emb,
                                                   const int* __restrict__ y,
                                                   float* __restrict__ cs,
                                                   float* __restrict__ cnt) {
    __shared__ unsigned msk[256];   // u32 per float4: byte j = class-nibble of element j
    __shared__ unsigned wcnt[4][2];
    int b = blockIdx.x >> 8;
    int base = (blockIdx.x & 255) << 10;
    int tid = threadIdx.x;
    int wave = tid >> 6, lane = tid & 63;
    int r = lane >> 4, q = lane & 15;

    // ---- phase A: masks + counts ----
    const int4* y0 = (const int4*)(y + ((size_t)(b * C_ + 0)) * V_ + base);
    const int4* y1 = (const int4*)(y + ((size_t)(b * C_ + 1)) * V_ + base);
    const int4* y2 = (const int4*)(y + ((size_t)(b * C_ + 2)) * V_ + base);
    const int4* y3 = (const int4*)(y + ((size_t)(b * C_ + 3)) * V_ + base);
    int4 ya = y0[tid], yb = y1[tid], yc = y2[tid], yd = y3[tid];

    unsigned b0 = (unsigned)(ya.x > 0) | ((unsigned)(yb.x > 0) << 1) | ((unsigned)(yc.x > 0) << 2) | ((unsigned)(yd.x > 0) << 3);
    unsigned b1 = (unsigned)(ya.y > 0) | ((unsigned)(yb.y > 0) << 1) | ((unsigned)(yc.y > 0) << 2) | ((unsigned)(yd.y > 0) << 3);
    unsigned b2 = (unsigned)(ya.z > 0) | ((unsigned)(yb.z > 0) << 1) | ((unsigned)(yc.z > 0) << 2) | ((unsigned)(yd.z > 0) << 3);
    unsigned b3 = (unsigned)(ya.w > 0) | ((unsigned)(yb.w > 0) << 1) | ((unsigned)(yc.w > 0) << 2) | ((unsigned)(yd.w > 0) << 3);
    msk[tid] = b0 | (b1 << 8) | (b2 << 16) | (b3 << 24);

    unsigned p01 = ((unsigned)(ya.x > 0) + (ya.y > 0) + (ya.z > 0) + (ya.w > 0))
                 | (((unsigned)(yb.x > 0) + (yb.y > 0) + (yb.z > 0) + (yb.w > 0)) << 16);
    unsigned p23 = ((unsigned)(yc.x > 0) + (yc.y > 0) + (yc.z > 0) + (yc.w > 0))
                 | (((unsigned)(yd.x > 0) + (yd.y > 0) + (yd.z > 0) + (yd.w > 0)) << 16);
    #pragma unroll
    for (int o = 1; o < 64; o <<= 1) {
        p01 += __shfl_xor(p01, o, 64);
        p23 += __shfl_xor(p23, o, 64);
    }
    if (lane == 0) { wcnt[wave][0] = p01; wcnt[wave][1] = p23; }
    __syncthreads();
    if (tid == 0) {
        unsigned q01 = wcnt[0][0] + wcnt[1][0] + wcnt[2][0] + wcnt[3][0];
        unsigned q23 = wcnt[0][1] + wcnt[1][1] + wcnt[2][1] + wcnt[3][1];
        atomicAdd(&cnt[0], (float)(q01 & 0xFFFFu));
        atomicAdd(&cnt[1], (float)(q01 >> 16));
        atomicAdd(&cnt[2], (float)(q23 & 0xFFFFu));
        atomicAdd(&cnt[3], (float)(q23 >> 16));
    }

    // ---- phase B ----
    #pragma unroll
    for (int p = 0; p < 4; ++p) {
        int f = (wave << 4) | (p << 2) | r;
        const float4* ep = (const float4*)(emb + ((size_t)(b * F_ + f)) * V_ + base);

        float4 e[16];
        unsigned mm[16];
        #pragma unroll
        for (int it = 0; it < 16; ++it) e[it] = ep[(it << 4) | q];
        #pragma unroll
        for (int it = 0; it < 16; ++it) mm[it] = msk[(it << 4) | q];

        float a0 = 0.f, a1 = 0.f, a2 = 0.f, a3 = 0.f;
        #pragma unroll
        for (int it = 0; it < 16; ++it) {
            unsigned m = mm[it];
            float4 ev = e[it];
            a0 += ev.x * (float)( m        & 1u) + ev.y * (float)((m >>  8) & 1u)
                + ev.z * (float)((m >> 16) & 1u) + ev.w * (float)((m >> 24) & 1u);
            a1 += ev.x * (float)((m >>  1) & 1u) + ev.y * (float)((m >>  9) & 1u)
                + ev.z * (float)((m >> 17) & 1u) + ev.w * (float)((m >> 25) & 1u);
            a2 += ev.x * (float)((m >>  2) & 1u) + ev.y * (float)((m >> 10) & 1u)
                + ev.z * (float)((m >> 18) & 1u) + ev.w * (float)((m >> 26) & 1u);
            a3 += ev.x * (float)((m >>  3) & 1u) + ev.y * (float)((m >> 11) & 1u)
                + ev.z * (float)((m >> 19) & 1u) + ev.w * (float)((m >> 27) & 1u);
        }
        // reduce across the 16 lanes (q) sharing this row
        #pragma unroll
        for (int o = 1; o < 16; o <<= 1) {
            a0 += __shfl_xor(a0, o, 64);
            a1 += __shfl_xor(a1, o, 64);
            a2 += __shfl_xor(a2, o, 64);
            a3 += __shfl_xor(a3, o, 64);
        }
        if (q == 0) {
            atomicAdd(&cs[0 * F_ + f], a0);
            atomicAdd(&cs[1 * F_ + f], a1);
            atomicAdd(&cs[2 * F_ + f], a2);
            atomicAdd(&cs[3 * F_ + f], a3);
        }
    }
}

__device__ __forceinline__ float weight_of(const float* __restrict__ p0, int v) {
    return ((p0[v] * p0[v + V_]) * p0[v + 2 * V_]) * p0[v + 3 * V_];
}

// level-1 histogram: top-8 bits of w; also materialize w bits for later passes
__global__ __launch_bounds__(256) void k_hist1(const float* __restrict__ proba,
                                               unsigned* __restrict__ hist1,
                                               unsigned* __restrict__ wbits) {
    __shared__ unsigned lh[256];
    int tid = threadIdx.x;
    lh[tid] = 0u;
    __syncthreads();
    int b = blockIdx.x >> 8;
    int base = (blockIdx.x & 255) << 10;
    const float* p0 = proba + (size_t)(b * C_) * V_;
    for (int it = 0; it < 4; ++it) {
        int v = base + tid + (it << 8);
        unsigned bits = __float_as_uint(weight_of(p0, v));
        wbits[(size_t)b * V_ + v] = bits;
        atomicAdd(&lh[bits >> 24], 1u);
    }
    __syncthreads();
    if (lh[tid]) atomicAdd(&hist1[b * 256 + tid], lh[tid]);
}

// level-2 histogram: next 8 bits, only for elements in bin T1 (reads wbits, 4 MB)
__global__ __launch_bounds__(256) void k_hist2(const unsigned* __restrict__ wbits,
                                               const unsigned* __restrict__ ctrl1,
                                               unsigned* __restrict__ hist2) {
    __shared__ unsigned lh[256];
    int tid = threadIdx.x;
    lh[tid] = 0u;
    __syncthreads();
    int b = blockIdx.x >> 8;
    int base = (blockIdx.x & 255) << 10;
    unsigned T1 = ctrl1[b * 2];
    for (int it = 0; it < 4; ++it) {
        int v = base + tid + (it << 8);
        unsigned bits = wbits[(size_t)b * V_ + v];
        if ((bits >> 24) == T1) atomicAdd(&lh[(bits >> 16) & 0xFF], 1u);
    }
    __syncthreads();
    if (lh[tid]) atomicAdd(&hist2[b * 256 + tid], lh[tid]);
}

// wave-parallel threshold finder over a 256-bin histogram (descending).
__global__ __launch_bounds__(256) void k_thresh(const unsigned* __restrict__ hist,
                                                const unsigned* __restrict__ ctrl_in,
                                                unsigned* __restrict__ ctrl_out,
                                                int lvl) {
    int b = threadIdx.x >> 6;
    int lane = threadIdx.x & 63;
    const unsigned* h = hist + b * 256;
    unsigned base = lvl ? ctrl_in[b * 2 + 1] : 0u;
    int binbase = 255 - 4 * lane;
    unsigned c0 = h[binbase], c1 = h[binbase - 1], c2 = h[binbase - 2], c3 = h[binbase - 3];
    unsigned cnt4 = c0 + c1 + c2 + c3;
    unsigned pref = cnt4;
    #pragma unroll
    for (int o = 1; o < 64; o <<= 1) {
        unsigned u = __shfl_up(pref, o, 64);
        if (lane >= o) pref += u;
    }
    unsigned above = base + pref - cnt4;
    unsigned t = above;
    int found = -1; unsigned nab = 0;
    if (t + c0 >= K_)                { found = binbase;     nab = t; }
    else if (t + c0 + c1 >= K_)      { found = binbase - 1; nab = t + c0; }
    else if (t + c0 + c1 + c2 >= K_) { found = binbase - 2; nab = t + c0 + c1; }
    else if (t + cnt4 >= K_)         { found = binbase - 3; nab = t + c0 + c1 + c2; }
    if (found >= 0 && above < K_) {
        ctrl_out[b * 2] = lvl ? ((ctrl_in[b * 2] << 8) | (unsigned)found) : (unsigned)found;
        ctrl_out[b * 2 + 1] = nab;
    }
}

// collect all candidates with (bits>>16) >= P16  (~K + one 16-bit bin)
__global__ __launch_bounds__(256) void k_collect(const unsigned* __restrict__ wbits,
                                                 const unsigned* __restrict__ ctrl2,
                                                 unsigned* __restrict__ ccount,
                                                 unsigned* __restrict__ cbits,
                                                 unsigned* __restrict__ cidx) {
    int b = blockIdx.x >> 8;
    int base = (blockIdx.x & 255) << 10;
    int tid = threadIdx.x;
    unsigned P16 = ctrl2[b * 2];
    for (int it = 0; it < 4; ++it) {
        int v = base + tid + (it << 8);
        unsigned bits = wbits[(size_t)b * V_ + v];
        if ((bits >> 16) >= P16) {
            unsigned pos = atomicAdd(&ccount[b], 1u);
            if (pos < CAP2) { cbits[b * CAP2 + pos] = bits; cidx[b * CAP2 + pos] = (unsigned)v; }
        }
    }
}

// exact top-K: one wave per b, lane-private LDS regions, zero barriers.
__global__ __launch_bounds__(64) void k_select(const unsigned* __restrict__ ccount,
                                               const unsigned* __restrict__ cbits,
                                               const unsigned* __restrict__ cidx,
                                               unsigned* __restrict__ idxout) {
    __shared__ ull keys[CAP2];
    int b = blockIdx.x;
    int lane = threadIdx.x;
    unsigned nc = ccount[b];
    int n = (int)(nc < CAP2 ? nc : CAP2);
    for (int i = lane; i < n; i += 64)
        keys[i] = ((ull)cbits[b * CAP2 + i] << 32) | (unsigned)(~cidx[b * CAP2 + i]);
    for (int k = 0; k < K_; ++k) {
        ull m = 0ull; int mslot = -1;
        for (int i = lane; i < n; i += 64) {
            ull key = keys[i];
            if (key > m) { m = key; mslot = i; }
        }
        ull lm = m;
        #pragma unroll
        for (int o = 1; o < 64; o <<= 1) {
            ull other = __shfl_xor(m, o, 64);
            if (other > m) m = other;
        }
        if (mslot >= 0 && lm == m) keys[mslot] = 0ull;
        if (lane == 0) idxout[b * K_ + k] = ~(unsigned)(m & 0xFFFFFFFFull);
    }
}

// final: one wave (64 lanes = F) per (b,k)
__global__ __launch_bounds__(64) void k_final(const float* __restrict__ emb,
                                              const int* __restrict__ y,
                                              const float* __restrict__ avg,
                                              const float* __restrict__ cs,
                                              const float* __restrict__ cnt,
                                              const unsigned* __restrict__ idxout,
                                              float* __restrict__ out) {
    int blk = blockIdx.x;
    int b = blk / K_;
    int k = blk % K_;
    int lane = threadIdx.x;
    unsigned v = idxout[b * K_ + k];

    float e = emb[((size_t)(b * F_ + lane)) * V_ + v];

    int y0v = y[((size_t)(b * C_ + 0)) * V_ + v];
    int y1v = y[((size_t)(b * C_ + 1)) * V_ + v];
    int y2v = y[((size_t)(b * C_ + 2)) * V_ + v];
    int y3v = y[((size_t)(b * C_ + 3)) * V_ + v];
    int cm = (y0v > 0) ? 0 : ((y1v > 0) ? 1 : ((y2v > 0) ? 2 : ((y3v > 0) ? 3 : 0)));
    float sel = (cm == 0) ? 1.f : 0.f;

    float t = e / TAU_;
    float ssum = 0.f;
    #pragma unroll
    for (int c = 1; c < 4; ++c) {
        float cc = cnt[c];
        float mean = cs[c * F_ + lane] / fmaxf(cc, 1.f);
        float av = avg[c * F_ + lane];
        float nar = (cc > 0.f) ? (av * (1.f - THETA) + mean * THETA) : av;
        ssum += expf(t * nar);
    }
    float term = -logf(ssum);
    #pragma unroll
    for (int o = 32; o > 0; o >>= 1) term += __shfl_down(term, o, 64);
    if (lane == 0) out[b * K_ + k] = term * sel;
}

extern "C" void kernel_launch(void* const* d_in, const int* in_sizes, int n_in,
                              void* d_out, int out_size, void* d_ws, size_t ws_size,
                              hipStream_t stream) {
    const float* proba = (const float*)d_in[0];
    const int* y = (const int*)d_in[1];
    const float* emb = (const float*)d_in[2];
    const float* avg = (const float*)d_in[3];
    float* out = (float*)d_out;

    char* ws = (char*)d_ws;
    float* cs = (float*)(ws + 0);
    float* cnt = (float*)(ws + 1024);
    unsigned* hist1 = (unsigned*)(ws + 2048);
    unsigned* hist2 = (unsigned*)(ws + 6144);
    unsigned* ctrl1 = (unsigned*)(ws + 10240);
    unsigned* ctrl2 = (unsigned*)(ws + 10272);
    unsigned* ccount = (unsigned*)(ws + 10304);
    unsigned* idxout = (unsigned*)(ws + 10368);
    unsigned* cbits = (unsigned*)(ws + 16384);
    unsigned* cidx = (unsigned*)(ws + 81920);
    unsigned* wbits = (unsigned*)(ws + 1048576);

    k_init<<<4, 256, 0, stream>>>(cs, cnt, hist1, hist2, ccount);
    k_class_sum<<<B_ * 256, 256, 0, stream>>>(emb, y, cs, cnt);
    k_hist1<<<B_ * 256, 256, 0, stream>>>(proba, hist1, wbits);
    k_thresh<<<1, 256, 0, stream>>>(hist1, nullptr, ctrl1, 0);
    k_hist2<<<B_ * 256, 256, 0, stream>>>(wbits, ctrl1, hist2);
    k_thresh<<<1, 256, 0, stream>>>(hist2, ctrl1, ctrl2, 1);
    k_collect<<<B_ * 256, 256, 0, stream>>>(wbits, ctrl2, ccount, cbits, cidx);
    k_select<<<B_, 64, 0, stream>>>(ccount, cbits, cidx, idxout);
    k_final<<<B_ * K_, 64, 0, stream>>>(emb, y, avg, cs, cnt, idxout, out);
}